// Round 1
// baseline (116.154 us; speedup 1.0000x reference)
//
#include <hip/hip_runtime.h>

// TwoRobots: x1 = x + (A1x + A2x + Bu)*H + w, elementwise over B=1e6 columns.
// Trig identities collapse: Fgx = -KS*dx - CD*vx ; Fgy = -KS*dy - CD*vy.
// Memory-bound: 112 B/column -> ~18 us floor at 6.3 TB/s.

#define H_STEP 0.05f
#define KSC    2.0f
#define CDC    2.0f

__global__ __launch_bounds__(256)
void two_robots_kernel(const float4* __restrict__ x4,
                       const float4* __restrict__ u4,
                       const float4* __restrict__ w4,
                       const float*  __restrict__ xbar,
                       float4* __restrict__ out4,
                       int nvec)  // nvec = B/4
{
    int i = blockIdx.x * blockDim.x + threadIdx.x;
    if (i >= nvec) return;

    // wave-uniform target positions (scalar loads, s_load path)
    const float xt0 = xbar[0], yt0 = xbar[1];
    const float xt1 = xbar[4], yt1 = xbar[5];

#pragma unroll
    for (int a = 0; a < 2; ++a) {
        const float xt = a ? xt1 : xt0;
        const float yt = a ? yt1 : yt0;
        const int rb = a * 4;          // x/w/out row base for this agent
        const int ub = a * 2;          // u row base

        float4 px = x4[(size_t)(rb + 0) * nvec + i];
        float4 py = x4[(size_t)(rb + 1) * nvec + i];
        float4 vx = x4[(size_t)(rb + 2) * nvec + i];
        float4 vy = x4[(size_t)(rb + 3) * nvec + i];
        float4 ux = u4[(size_t)(ub + 0) * nvec + i];
        float4 uy = u4[(size_t)(ub + 1) * nvec + i];
        float4 w0 = w4[(size_t)(rb + 0) * nvec + i];
        float4 w1 = w4[(size_t)(rb + 1) * nvec + i];
        float4 w2 = w4[(size_t)(rb + 2) * nvec + i];
        float4 w3 = w4[(size_t)(rb + 3) * nvec + i];

        float4 o0, o1, o2, o3;
#define LANE(c)                                                              \
        o0.c = px.c + vx.c * H_STEP + w0.c;                                  \
        o1.c = py.c + vy.c * H_STEP + w1.c;                                  \
        o2.c = vx.c + (-KSC * (px.c - xt) - CDC * vx.c + ux.c) * H_STEP + w2.c; \
        o3.c = vy.c + (-KSC * (py.c - yt) - CDC * vy.c + uy.c) * H_STEP + w3.c;
        LANE(x) LANE(y) LANE(z) LANE(w)
#undef LANE

        out4[(size_t)(rb + 0) * nvec + i] = o0;
        out4[(size_t)(rb + 1) * nvec + i] = o1;
        out4[(size_t)(rb + 2) * nvec + i] = o2;
        out4[(size_t)(rb + 3) * nvec + i] = o3;
    }
}

extern "C" void kernel_launch(void* const* d_in, const int* in_sizes, int n_in,
                              void* d_out, int out_size, void* d_ws, size_t ws_size,
                              hipStream_t stream) {
    const float* x    = (const float*)d_in[0];   // (8, B)
    const float* u    = (const float*)d_in[1];   // (4, B)
    const float* w    = (const float*)d_in[2];   // (8, B)
    const float* xbar = (const float*)d_in[3];   // (8,)
    // d_in[4] = t (unused)
    float* out = (float*)d_out;                  // (8, B)

    const int B = in_sizes[0] / 8;               // 1,000,000 (divisible by 4)
    const int nvec = B / 4;
    const int block = 256;
    const int grid = (nvec + block - 1) / block;

    two_robots_kernel<<<grid, block, 0, stream>>>(
        (const float4*)x, (const float4*)u, (const float4*)w, xbar,
        (float4*)out, nvec);
}